// Round 1
// baseline (35.278 us; speedup 1.0000x reference)
//
#include <hip/hip_runtime.h>
#include <math.h>

#define CHF_STEP 32
#define S2 64        // 2*CHF_STEP
#define HH 128
#define WW 128
#define BB 16
#define CHF_TIK 0.05f

// One block per (b,u). 128 threads.
// Phase A: thread t = w, reduce over h -> Cr[w], Ci[w] in LDS.
// Phase B: thread t -> (v = t&63, half = t>>6), reduce over 64 w's each,
//          combine halves in LDS, diff vs chf, squared-error wave-reduce,
//          atomicAdd into per-batch sum.
__global__ __launch_bounds__(128) void chf_main(const float* __restrict__ dnn,
                                                const float* __restrict__ chf,
                                                float* __restrict__ sums) {
    const int b = blockIdx.x >> 6;   // 0..15
    const int u = blockIdx.x & 63;   // 0..63
    const int t = threadIdx.x;       // 0..127

    __shared__ float cb[HH], sb[HH];   // cos/sin(freq[u]*(h+0.5))
    __shared__ float crw[WW], ciw[WW]; // stage-A outputs
    __shared__ float pr[128], pi[128]; // stage-B partials

    const float fu = (float)(u - CHF_STEP) * CHF_TIK;

    // Build the stage-A trig table: one sincos per thread (h = t).
    {
        float s, c;
        sincosf(fu * ((float)t + 0.5f), &s, &c);
        cb[t] = c;
        sb[t] = s;
    }
    __syncthreads();

    // ---- Phase A: w = t, reduce over h (coalesced dnn row loads) ----
    const float* dptr = dnn + (size_t)b * (HH * WW) + t;
    float ar = 0.0f, ai = 0.0f;
#pragma unroll 8
    for (int h = 0; h < HH; ++h) {
        float d = dptr[(size_t)h * WW];
        ar = fmaf(cb[h], d, ar);
        ai = fmaf(sb[h], d, ai);
    }
    crw[t] = ar;
    ciw[t] = ai;
    __syncthreads();

    // ---- Phase B: v = t&63, each half-thread covers 64 w values ----
    const int v = t & 63;
    const int half = t >> 6;
    const float fv = (float)(v - CHF_STEP) * CHF_TIK;
    float rr = 0.0f, ri = 0.0f;
    const int w0 = half * 64;
#pragma unroll 4
    for (int j = 0; j < 64; ++j) {
        const int w = w0 + j;
        float s, c;
        sincosf(fv * ((float)w + 0.5f), &s, &c);
        const float cr = crw[w];
        const float ci = ciw[w];
        rr = fmaf(c, cr, fmaf(-s, ci, rr));
        ri = fmaf(s, cr, fmaf(c, ci, ri));
    }
    pr[t] = rr;
    pi[t] = ri;
    __syncthreads();

    // ---- Combine halves, diff vs chf, squared error, reduce ----
    if (t < 64) {
        const float real = pr[t] + pr[t + 64];
        const float img  = pi[t] + pi[t + 64];
        const float2 cf = *(const float2*)(chf + ((((size_t)b * S2 + u) * S2 + t) * 2));
        const float d0 = real - cf.x;
        const float d1 = img - cf.y;
        float sq = fmaf(d0, d0, d1 * d1);
        // threads 0..63 are exactly one wave64
#pragma unroll
        for (int off = 32; off; off >>= 1)
            sq += __shfl_down(sq, off, 64);
        if (t == 0) atomicAdd(&sums[b], sq);
    }
}

__global__ __launch_bounds__(64) void chf_final(const float* __restrict__ sums,
                                                float* __restrict__ out) {
    const int t = threadIdx.x; // 64 threads, one wave
    float v = (t < BB) ? sqrtf(sums[t]) : 0.0f;
#pragma unroll
    for (int off = 32; off; off >>= 1)
        v += __shfl_down(v, off, 64);
    if (t == 0) out[0] = v * (CHF_TIK / (float)BB);
}

extern "C" void kernel_launch(void* const* d_in, const int* in_sizes, int n_in,
                              void* d_out, int out_size, void* d_ws, size_t ws_size,
                              hipStream_t stream) {
    const float* dnn = (const float*)d_in[0]; // (16,128,128) f32
    const float* chf = (const float*)d_in[1]; // (16,64,64,2) f32
    float* out = (float*)d_out;               // scalar f32
    float* sums = (float*)d_ws;               // 16 floats of scratch

    hipMemsetAsync(sums, 0, BB * sizeof(float), stream);
    chf_main<<<dim3(BB * S2), dim3(128), 0, stream>>>(dnn, chf, sums);
    chf_final<<<dim3(1), dim3(64), 0, stream>>>(sums, out);
}

// Round 2
// 13.138 us; speedup vs baseline: 2.6853x; 2.6853x over previous
//
#include <hip/hip_runtime.h>
#include <math.h>

#define S2 64
#define HH 128
#define WW 128
#define BB 16
#define TIK 0.05f

// One block per (b,u), 256 threads (4 waves).
// Phase A: thread t -> (hgroup = t>>5, w4 = (t&31)*4); each thread reduces 16 h's
//          for 4 w columns via float4 loads; combine the 8 h-groups in LDS.
// Phase B: thread t -> (v = t&63, quarter = t>>6); 32-step complex rotation
//          recurrence replaces per-step sincosf; combine quarters in LDS.
// Output: per-block squared-error sum -> partials[blockIdx.x] (no atomics).
__global__ __launch_bounds__(256) void chf_main(const float* __restrict__ dnn,
                                                const float* __restrict__ chf,
                                                float* __restrict__ partials) {
    const int b = blockIdx.x >> 6;   // 0..15
    const int u = blockIdx.x & 63;   // 0..63
    const int t = threadIdx.x;       // 0..255

    __shared__ float cb[HH], sb[HH];          // cos/sin(fu*(h+0.5))
    __shared__ float a2r[8 * WW], a2i[8 * WW]; // phase-A partials per h-group
    __shared__ float crw[WW], ciw[WW];         // stage-A outputs
    __shared__ float pr[256], pi[256];         // phase-B partials

    const float fu = (float)(u - 32) * TIK;

    if (t < HH) {
        float s, c;
        sincosf(fu * ((float)t + 0.5f), &s, &c);
        cb[t] = c;
        sb[t] = s;
    }
    __syncthreads();

    // ---- Phase A: 8 h-groups x 16 h each; float4 over 4 w columns ----
    {
        const int hg = t >> 5;          // 0..7
        const int w4 = (t & 31) << 2;   // 0,4,...,124
        const float4* drow = (const float4*)(dnn + (size_t)b * HH * WW);
        float ar0 = 0, ar1 = 0, ar2 = 0, ar3 = 0;
        float ai0 = 0, ai1 = 0, ai2 = 0, ai3 = 0;
#pragma unroll
        for (int j = 0; j < 16; ++j) {
            const int h = hg * 16 + j;
            const float4 d = drow[h * (WW / 4) + (w4 >> 2)];
            const float ch = cb[h], sh = sb[h];
            ar0 = fmaf(ch, d.x, ar0); ai0 = fmaf(sh, d.x, ai0);
            ar1 = fmaf(ch, d.y, ar1); ai1 = fmaf(sh, d.y, ai1);
            ar2 = fmaf(ch, d.z, ar2); ai2 = fmaf(sh, d.z, ai2);
            ar3 = fmaf(ch, d.w, ar3); ai3 = fmaf(sh, d.w, ai3);
        }
        float4* wr = (float4*)&a2r[hg * WW + w4];
        float4* wi = (float4*)&a2i[hg * WW + w4];
        *wr = make_float4(ar0, ar1, ar2, ar3);
        *wi = make_float4(ai0, ai1, ai2, ai3);
    }
    __syncthreads();

    if (t < WW) {
        float sr = 0, si = 0;
#pragma unroll
        for (int g = 0; g < 8; ++g) {
            sr += a2r[g * WW + t];
            si += a2i[g * WW + t];
        }
        crw[t] = sr;
        ciw[t] = si;
    }
    __syncthreads();

    // ---- Phase B: rotation recurrence over 32 w's per thread ----
    {
        const int v = t & 63;
        const int q = t >> 6;  // 0..3
        const float fv = (float)(v - 32) * TIK;
        float s0, c0, ss, cs;
        sincosf(fv * ((float)(q * 32) + 0.5f), &s0, &c0);  // angle at w = q*32
        sincosf(fv, &ss, &cs);                              // per-step rotation
        float c = c0, s = s0;
        float rr = 0, ri = 0;
#pragma unroll
        for (int j = 0; j < 32; ++j) {
            const int w = q * 32 + j;
            const float cr = crw[w], ci = ciw[w];
            rr = fmaf(c, cr, rr); rr = fmaf(-s, ci, rr);
            ri = fmaf(s, cr, ri); ri = fmaf(c, ci, ri);
            const float cn = fmaf(c, cs, -s * ss);
            s = fmaf(s, cs, c * ss);   // uses old c (cn not yet assigned)
            c = cn;
        }
        pr[t] = rr;
        pi[t] = ri;
    }
    __syncthreads();

    // ---- Combine quarters, diff vs chf, squared error, wave reduce ----
    if (t < 64) {
        const float real = pr[t] + pr[t + 64] + pr[t + 128] + pr[t + 192];
        const float img  = pi[t] + pi[t + 64] + pi[t + 128] + pi[t + 192];
        const float2 cf = *(const float2*)(chf + ((((size_t)b * S2 + u) * S2 + t) * 2));
        const float d0 = real - cf.x;
        const float d1 = img - cf.y;
        float sq = fmaf(d0, d0, d1 * d1);
#pragma unroll
        for (int off = 32; off; off >>= 1)
            sq += __shfl_down(sq, off, 64);
        if (t == 0) partials[blockIdx.x] = sq;
    }
}

// 1 block x 1024 threads: wave w reduces the 64 partials of batch b = w.
__global__ __launch_bounds__(1024) void chf_final(const float* __restrict__ partials,
                                                  float* __restrict__ out) {
    const int t = threadIdx.x;  // 0..1023
    __shared__ float red[BB];
    float v = partials[t];
#pragma unroll
    for (int off = 32; off; off >>= 1)
        v += __shfl_down(v, off, 64);
    if ((t & 63) == 0) red[t >> 6] = sqrtf(v);
    __syncthreads();
    if (t == 0) {
        float acc = 0;
#pragma unroll
        for (int i = 0; i < BB; ++i) acc += red[i];
        out[0] = acc * (TIK / (float)BB);
    }
}

extern "C" void kernel_launch(void* const* d_in, const int* in_sizes, int n_in,
                              void* d_out, int out_size, void* d_ws, size_t ws_size,
                              hipStream_t stream) {
    const float* dnn = (const float*)d_in[0];  // (16,128,128) f32
    const float* chf = (const float*)d_in[1];  // (16,64,64,2) f32
    float* out = (float*)d_out;                // scalar f32
    float* partials = (float*)d_ws;            // 1024 floats, fully overwritten

    chf_main<<<dim3(BB * S2), dim3(256), 0, stream>>>(dnn, chf, partials);
    chf_final<<<dim3(1), dim3(1024), 0, stream>>>(partials, out);
}